// Round 8
// baseline (739.447 us; speedup 1.0000x reference)
//
#include <hip/hip_runtime.h>

#define NGR 4096
#define NPG 24
#define EPG 48
#define LPG 144
#define NITER 4
#define HID 128
#define NN (NGR*NPG)
#define NE (NGR*EPG)
#define NL (NGR*LPG)

typedef unsigned int uint;
typedef unsigned short ushort;
typedef short bf16x8 __attribute__((ext_vector_type(8)));
typedef unsigned short u16x4 __attribute__((ext_vector_type(4)));
typedef float f32x4 __attribute__((ext_vector_type(4)));
typedef float f32x2 __attribute__((ext_vector_type(2)));

__device__ __forceinline__ float b2f(ushort u){ return __uint_as_float(((uint)u)<<16); }
__device__ __forceinline__ ushort f2b(float f){
  uint x = __float_as_uint(f);
  x += 0x7FFFu + ((x>>16)&1u);
  return (ushort)(x>>16);
}
__device__ __forceinline__ float wredsum(float v){
  #pragma unroll
  for(int m=32;m;m>>=1) v += __shfl_xor(v, m, 64);
  return v;
}
__device__ __forceinline__ f32x4 mfma16(bf16x8 a, bf16x8 b, f32x4 c){
  return __builtin_amdgcn_mfma_f32_16x16x32_bf16(a, b, c, 0, 0, 0);
}

// ---------------------------------------------------------------------------
// k_prep: split weights into bf16 hi/lo, transposed [n][k], into ws.
// ushort offsets in P: WmH 0, WmL 12288, WuH 24576, WuL 40960,
//                      WvH 57344, WvL 73728, WbH 90112, WbL 106496
// ---------------------------------------------------------------------------
__global__ __launch_bounds__(256) void k_prep(
    const float* __restrict__ wmlp, const float* __restrict__ wu,
    const float* __restrict__ wv, const float* __restrict__ wb,
    ushort* __restrict__ P)
{
  int id = blockIdx.x*256 + threadIdx.x;
  if(id < 12288){
    int n=id/96, k=id-n*96;
    float v=(k<70)? wmlp[k*128+n] : 0.f;
    ushort hb=f2b(v); P[id]=hb; P[12288+id]=f2b(v-b2f(hb));
  } else if(id < 28672){
    int i=id-12288, n=i>>7, k=i&127;
    float v=wu[k*128+n]; ushort hb=f2b(v);
    P[24576+i]=hb; P[40960+i]=f2b(v-b2f(hb));
  } else if(id < 45056){
    int i=id-28672, n=i>>7, k=i&127;
    float v=wv[k*128+n]; ushort hb=f2b(v);
    P[57344+i]=hb; P[73728+i]=f2b(v-b2f(hb));
  } else if(id < 61440){
    int i=id-45056, n=i>>7, k=i&127;
    float v=wb[k*128+n]; ushort hb=f2b(v);
    P[90112+i]=hb; P[106496+i]=f2b(v-b2f(hb));
  }
}

// ---------------------------------------------------------------------------
// k_fused R8: 512 threads/graph, 8 waves x 16 feature cols each (nt loop
// eliminated). R3-R7 all hit the same spill equilibrium (VGPR=84 arch +
// 84 AGPR static partition at (256,3); ~28 dwords/thread scratch). Halving
// per-thread state (e0f 24->12 etc.) drops arch demand below any partition:
// __launch_bounds__(512,4) -> 2 blocks/CU, 16 decorrelated waves, no spill.
// Per-wave MFMA chain also halves. Algorithm/numerics identical to R7.
// ---------------------------------------------------------------------------
__global__ __launch_bounds__(512,4) void k_fused(
  const float* __restrict__ x, const float* __restrict__ ea,
  const int* __restrict__ eidx, const int* __restrict__ lidx,
  const ushort* __restrict__ P,
  const float* __restrict__ bmlp, const float* __restrict__ wedge,
  const float* __restrict__ wrel, const float* __restrict__ brel,
  const float* __restrict__ wroot,
  const float* __restrict__ aatt, const float* __restrict__ abias,
  const float* __restrict__ wgout, const float* __restrict__ bgout,
  const float* __restrict__ bblock,
  float* __restrict__ out)
{
  const int g=blockIdx.x, tid=threadIdx.x, lane=tid&63, wid=tid>>6;
  const int q=lane>>4, ln=lane&15;
  const int E0=g*EPG, L0=g*LPG;
  const int nA = wid*16 + ln;          // this wave owns feature cols [16w,16w+16)

  __shared__ __align__(16) char LB[48320];
  ushort* Hh   = (ushort*)(LB + 0);      // h / z split hi, [24][136]
  ushort* Hl   = (ushort*)(LB + 6528);   // -> 13056
  ushort* A_bf = (ushort*)(LB + 13056);  // [48][56], cols 0..47 valid -> 18432
  ushort* OUTh = (ushort*)(LB + 18432);  // [128][48] split-hi recursion buffer
  ushort* OUTl = (ushort*)(LB + 30720);  // [128][48] split-lo -> 43008
  // aliases inside OUT region (18432..43008), sequential in time:
  ushort* A_cnt= (ushort*)(LB + 18432);  // [48][64] packed ushort counts
  ushort* xh   = (ushort*)(LB + 18432);  // [32][96]
  ushort* xl   = (ushort*)(LB + 24576);
  float*  Pe   = (float*) (LB + 30720);  // [48]   dead before pass1
  float*  Re   = (float*) (LB + 30912);  // [48]
  float*  eaL  = (float*) (LB + 31104);  // [48][6] -> 32256
  float*  nacc = (float*) (LB + 18432);  // [24][128] (after last OUT read)
  int*    esrc = (int*)   (LB + 43008);
  int*    edst = (int*)   (LB + 43200);
  float*  xcs  = (float*) (LB + 43392);  // [4][48] -> 44160
  float*  gsf  = (float*) (LB + 44160);  // [4][128] -> 46208
  float*  sfull= (float*) (LB + 46208);  // [4][128] -> 48256
  float*  score= (float*) (LB + 48256);
  float*  wts  = (float*) (LB + 48272);
  float*  zeroF= (float*) (LB + 48288);  // 8 zero floats (16B-aligned)

  const ushort *WmH=P, *WmL=P+12288, *WuH=P+24576, *WuL=P+40960,
               *WvH=P+57344, *WvL=P+73728, *WbH=P+90112, *WbL=P+106496;
  const f32x4 z4 = {0.f,0.f,0.f,0.f};

  // ---- phase 1a: x preload (regs), indices, ea, zeros, A counts ----
  f32x2 gxa[2];
  const f32x2* xg2 = (const f32x2*)(x + (size_t)g*NPG*70);
  #pragma unroll
  for(int i=0;i<2;i++){ int idx=tid+512*i; if(idx<840) gxa[i]=xg2[idx]; }
  for(int idx=tid; idx<1536; idx+=512) ((uint*)A_cnt)[idx]=0u;
  if(tid<48){
    int s=eidx[E0+tid]-g*NPG, d=eidx[NE+E0+tid]-g*NPG;
    esrc[tid]=s; edst[tid]=d; Pe[tid]=0.f; Re[tid]=0.f;
  }
  if(tid<8) zeroF[tid]=0.f;
  if(tid<288) eaL[tid]=ea[(size_t)E0*6+tid];
  if(tid<512) sfull[tid]=0.f;
  __syncthreads();
  if(tid<LPG){ int ls=lidx[L0+tid]-E0, ld=lidx[NL+L0+tid]-E0;
    atomicAdd(((uint*)A_cnt) + ((ld*64+ls)>>1), 1u<<((ls&1)*16)); }
  __syncthreads();
  // ---- 1b: counts -> A_bf [48][56] (cols 0..47; pad cols never read) ----
  for(int idx=tid; idx<48*48; idx+=512){ int i=idx/48, j=idx-i*48;
    A_bf[i*56+j]=f2b((float)A_cnt[i*64+j]); }
  __syncthreads();
  // ---- 1c: stage x into xh/xl (overwrites A_cnt region) ----
  #pragma unroll
  for(int i=0;i<2;i++){ int idx=tid+512*i; if(idx<840){
    int r=idx/35, c0=2*(idx-r*35);
    float v0=gxa[i].x, v1=gxa[i].y;
    ushort h0=f2b(v0), h1=f2b(v1);
    xh[r*96+c0]=h0;   xl[r*96+c0]=f2b(v0-b2f(h0));
    xh[r*96+c0+1]=h1; xl[r*96+c0+1]=f2b(v1-b2f(h1)); } }
  for(int idx=tid; idx<624; idx+=512){ int r=idx/26, c=70+(idx-r*26);
    xh[r*96+c]=0; xl[r*96+c]=0; }          // rows 24..31 left as finite garbage
  __syncthreads();

  // ---- GEMM1: h = x@wmlp + b  (bf16x3, K=96 padded; 1 col-group/wave) ----
  {
    f32x4 hc[2];
    hc[0]=z4; hc[1]=z4;
    #pragma unroll
    for(int kt=0; kt<3; kt++){
      int ko=kt*32+q*8;
      bf16x8 ah0=*(const bf16x8*)&xh[ln*96+ko];
      bf16x8 ah1=*(const bf16x8*)&xh[(16+ln)*96+ko];
      bf16x8 al0=*(const bf16x8*)&xl[ln*96+ko];
      bf16x8 al1=*(const bf16x8*)&xl[(16+ln)*96+ko];
      int nb=nA*96+ko;
      bf16x8 bh=*(const bf16x8*)&WmH[nb];
      bf16x8 bl=*(const bf16x8*)&WmL[nb];
      hc[0]=mfma16(ah0,bh,hc[0]);
      hc[0]=mfma16(al0,bh,hc[0]);
      hc[0]=mfma16(ah0,bl,hc[0]);
      hc[1]=mfma16(ah1,bh,hc[1]);
      hc[1]=mfma16(al1,bh,hc[1]);
      hc[1]=mfma16(ah1,bl,hc[1]);
    }
    float bb=bmlp[nA];
    #pragma unroll
    for(int mt=0;mt<2;mt++)
      #pragma unroll
      for(int r=0;r<4;r++){
        int row=mt*16+q*4+r;
        if(row<24){
          float hvv=hc[mt][r]+bb;
          ushort hb=f2b(hvv);
          Hh[row*136+nA]=hb; Hl[row*136+nA]=f2b(hvv-b2f(hb));
        }
      }
  }
  __syncthreads();

  // ---- e0 as gathered GEMM: e0 = (h[src]@wu + h[dst]@wv + ea@wedge)/3 ----
  f32x4 e0f[3];
  {
    int sgm[3], dgm[3];
    #pragma unroll
    for(int mt=0;mt<3;mt++){ sgm[mt]=esrc[mt*16+ln]; dgm[mt]=edst[mt*16+ln]; }
    #pragma unroll
    for(int mt=0;mt<3;mt++) e0f[mt]=z4;
    #pragma unroll
    for(int kt=0;kt<4;kt++){
      int ko=kt*32+q*8;
      int nb=nA*128+ko;
      bf16x8 BuH=*(const bf16x8*)&WuH[nb], BuL=*(const bf16x8*)&WuL[nb];
      bf16x8 BvH=*(const bf16x8*)&WvH[nb], BvL=*(const bf16x8*)&WvL[nb];
      #pragma unroll
      for(int mt=0;mt<3;mt++){
        bf16x8 ash=*(const bf16x8*)&Hh[sgm[mt]*136+ko];
        bf16x8 asl=*(const bf16x8*)&Hl[sgm[mt]*136+ko];
        bf16x8 adh=*(const bf16x8*)&Hh[dgm[mt]*136+ko];
        bf16x8 adl=*(const bf16x8*)&Hl[dgm[mt]*136+ko];
        f32x4 acc=e0f[mt];
        acc=mfma16(ash,BuH,acc);
        acc=mfma16(asl,BuH,acc);
        acc=mfma16(ash,BuL,acc);
        acc=mfma16(adh,BvH,acc);
        acc=mfma16(adl,BvH,acc);
        acc=mfma16(adh,BvL,acc);
        e0f[mt]=acc;
      }
    }
  }
  // ea@wedge term + /3, then Pe/Re partials
  {
    const float wrel0=wrel[nA];
    const float wroot0=wroot[nA];
    float wed0[6];
    #pragma unroll
    for(int k=0;k<6;k++) wed0[k]=wedge[k*128+nA];
    #pragma unroll
    for(int mt=0;mt<3;mt++)
      #pragma unroll
      for(int r=0;r<4;r++){
        int m=mt*16+q*4+r;
        float v0=e0f[mt][r];
        #pragma unroll
        for(int k=0;k<6;k++) v0+=eaL[m*6+k]*wed0[k];
        e0f[mt][r]=v0*(1.f/3.f);
      }
    #pragma unroll
    for(int mt=0;mt<3;mt++)
      #pragma unroll
      for(int r=0;r<4;r++){
        float pp=e0f[mt][r]*wrel0;
        float rr=e0f[mt][r]*wroot0;
        #pragma unroll
        for(int msk=1;msk<16;msk<<=1){ pp+=__shfl_xor(pp,msk,64); rr+=__shfl_xor(rr,msk,64); }
        if(ln==0){ atomicAdd(&Pe[mt*16+q*4+r],pp); atomicAdd(&Re[mt*16+q*4+r],rr); }
      }
  }
  __syncthreads();

  // ---- wave0: xcs softmaxes (scores recursion on Pe/Re) ----
  if(wid==0){
    const float brel_f=brel[0];
    const int arow=(lane<48)?lane:0;
    float pprev=(lane<48)?Pe[lane]:0.f;
    float rprev=(lane<48)?Re[lane]:0.f;
    const float pe_l=pprev, re_l=rprev;
    float rlast=rprev;
    #pragma unroll
    for(int t=1;t<=5;t++){
      float s=0.f, sr=0.f;
      for(int j=0;j<48;j++){
        float a=b2f(A_bf[arow*56+j]);
        float pj=__shfl(pprev,j,64);
        float rj=__shfl(rprev,j,64);
        s+=a*pj; sr+=a*rj;
      }
      s+=pe_l; sr+=re_l;
      if(t>=2){
        float xv = s - pe_l + rlast + brel_f;
        float v=(lane<48)?xv:-3.0e38f;
        float mx=v;
        #pragma unroll
        for(int msk=32;msk;msk>>=1) mx=fmaxf(mx,__shfl_xor(mx,msk,64));
        float e2=(lane<48)?__expf(v-mx):0.f;
        float ss=e2;
        #pragma unroll
        for(int msk=32;msk;msk>>=1) ss+=__shfl_xor(ss,msk,64);
        if(lane<48) xcs[(t-2)*48+lane]=e2/ss;
      }
      pprev=s; rprev=sr; rlast=sr;
    }
  }
  __syncthreads();   // Pe/Re/eaL dead; OUT region free; xcs ready

  // ---- recursion helpers (swizzled split store/load, wave-private) ----
  // OUT[n][k]: row n (feature col), col k (edge). 16B block b of row n is
  // stored at block b ^ ((n>>3)&1). Each wave owns 16 rows (nA).
  #define STORE_SPLIT(n_, mt_, v_) {                                        \
    int b_ = (mt_)*2 + (q>>1);                                              \
    int off_ = (n_)*48 + ((b_ ^ (((n_)>>3)&1))<<3) + ((q&1)<<2);            \
    u16x4 hh_, ll_;                                                         \
    _Pragma("unroll")                                                       \
    for(int r_=0;r_<4;r_++){ ushort h_=f2b((v_)[r_]);                       \
      hh_[r_]=h_; ll_[r_]=f2b((v_)[r_]-b2f(h_)); }                          \
    *(u16x4*)&OUTh[off_]=hh_; *(u16x4*)&OUTl[off_]=ll_; }

  // ---- pass1: out_t = e0 + A@out_{t-1}; split-bf16 LDS round-trip ----
  f32x4 Ocur[3];
  #pragma unroll
  for(int mt=0;mt<3;mt++) STORE_SPLIT(nA, mt, e0f[mt]);
  const int swA=(nA>>3)&1, baseA=nA*48;
  #pragma unroll 1
  for(int t=0;t<NITER;t++){
    bf16x8 Bh0=*(const bf16x8*)&OUTh[baseA+((q^swA)<<3)];
    bf16x8 Bl0=*(const bf16x8*)&OUTl[baseA+((q^swA)<<3)];
    const ushort* ph1=(q<2)? &OUTh[baseA+(((4+q)^swA)<<3)] : (const ushort*)zeroF;
    const ushort* pl1=(q<2)? &OUTl[baseA+(((4+q)^swA)<<3)] : (const ushort*)zeroF;
    bf16x8 Bh1=*(const bf16x8*)ph1;
    bf16x8 Bl1=*(const bf16x8*)pl1;
    #pragma unroll
    for(int mt=0;mt<3;mt++){
      int ar=(mt*16+ln)*56;
      bf16x8 a0=*(const bf16x8*)&A_bf[ar+q*8];
      const ushort* pa1=(q<2)? &A_bf[ar+32+q*8] : (const ushort*)zeroF;
      bf16x8 a1=*(const bf16x8*)pa1;
      f32x4 acc=e0f[mt];
      acc=mfma16(a0,Bh0,acc);
      acc=mfma16(a1,Bh1,acc);
      acc=mfma16(a0,Bl0,acc);
      acc=mfma16(a1,Bl1,acc);
      Ocur[mt]=acc;
    }
    #pragma unroll
    for(int mt=0;mt<3;mt++) STORE_SPLIT(nA, mt, Ocur[mt]);
    float gp0=0.f;
    #pragma unroll
    for(int mt=0;mt<3;mt++)
      #pragma unroll
      for(int r=0;r<4;r++)
        gp0+=xcs[t*48+mt*16+q*4+r]*Ocur[mt][r];
    gp0+=__shfl_xor(gp0,16,64); gp0+=__shfl_xor(gp0,32,64);
    if(q==0) gsf[t*128+nA]=gp0;
  }
  __syncthreads();

  // ---- cooperative g@wgout partials (each wave: its own 16-k slab) ----
  {
    float p00=0,p01=0,p10=0,p11=0,p20=0,p21=0,p30=0,p31=0;
    int k0=wid*16;
    for(int kk=0;kk<16;kk++){
      int k=k0+kk;
      f32x2 w=((const f32x2*)wgout)[k*64+lane];
      float g0=gsf[k], g1=gsf[128+k], g2=gsf[256+k], g3=gsf[384+k];
      p00+=g0*w.x; p01+=g0*w.y;
      p10+=g1*w.x; p11+=g1*w.y;
      p20+=g2*w.x; p21+=g2*w.y;
      p30+=g3*w.x; p31+=g3*w.y;
    }
    atomicAdd(&sfull[2*lane],p00);     atomicAdd(&sfull[2*lane+1],p01);
    atomicAdd(&sfull[128+2*lane],p10); atomicAdd(&sfull[128+2*lane+1],p11);
    atomicAdd(&sfull[256+2*lane],p20); atomicAdd(&sfull[256+2*lane+1],p21);
    atomicAdd(&sfull[384+2*lane],p30); atomicAdd(&sfull[384+2*lane+1],p31);
  }
  __syncthreads();
  if(wid<4){
    int t=wid;
    float s0v=sfull[t*128+2*lane]  +bgout[2*lane];
    float s1v=sfull[t*128+2*lane+1]+bgout[2*lane+1];
    float v=tanhf(s0v)*aatt[(2*lane)*4+t]+tanhf(s1v)*aatt[(2*lane+1)*4+t];
    v=wredsum(v);
    if(lane==0) score[t]=v+abias[t];
  }
  __syncthreads();
  if(tid==0){
    float m=fmaxf(fmaxf(score[0],score[1]),fmaxf(score[2],score[3]));
    float e0v=__expf(score[0]-m), e1v=__expf(score[1]-m),
          e2v=__expf(score[2]-m), e3v=__expf(score[3]-m);
    float s=e0v+e1v+e2v+e3v;
    wts[0]=e0v/s; wts[1]=e1v/s; wts[2]=e2v/s; wts[3]=e3v/s;
  }
  __syncthreads();

  // ---- pass2 (Horner): y = sum_i c_i A^i e0, same LDS round-trip ----
  // out_t = sum_{i<=t} A^i e0  =>  sum_t w_t out_t = sum_i c_i A^i e0 with
  // c4=w4, c3=w3+w4, c2=w2+w3+w4, c1=c0=1.
  {
    const float cc4=wts[3], cc3=cc4+wts[2], cc2=cc3+wts[1];
    f32x4 Z[3];
    #pragma unroll
    for(int mt=0;mt<3;mt++){
      #pragma unroll
      for(int r=0;r<4;r++) Z[mt][r]=cc4*e0f[mt][r];
      STORE_SPLIT(nA, mt, Z[mt]);
    }
    #pragma unroll 1
    for(int s=0;s<NITER;s++){
      const float ci = (s==0)?cc3:(s==1)?cc2:1.f;
      bf16x8 Bh0=*(const bf16x8*)&OUTh[baseA+((q^swA)<<3)];
      bf16x8 Bl0=*(const bf16x8*)&OUTl[baseA+((q^swA)<<3)];
      const ushort* ph1=(q<2)? &OUTh[baseA+(((4+q)^swA)<<3)] : (const ushort*)zeroF;
      const ushort* pl1=(q<2)? &OUTl[baseA+(((4+q)^swA)<<3)] : (const ushort*)zeroF;
      bf16x8 Bh1=*(const bf16x8*)ph1;
      bf16x8 Bl1=*(const bf16x8*)pl1;
      #pragma unroll
      for(int mt=0;mt<3;mt++){
        int ar=(mt*16+ln)*56;
        bf16x8 a0=*(const bf16x8*)&A_bf[ar+q*8];
        const ushort* pa1=(q<2)? &A_bf[ar+32+q*8] : (const ushort*)zeroF;
        bf16x8 a1=*(const bf16x8*)pa1;
        f32x4 acc;
        #pragma unroll
        for(int r=0;r<4;r++) acc[r]=ci*e0f[mt][r];
        acc=mfma16(a0,Bh0,acc);
        acc=mfma16(a1,Bh1,acc);
        acc=mfma16(a0,Bl0,acc);
        acc=mfma16(a1,Bl1,acc);
        Z[mt]=acc;
      }
      if(s<NITER-1){
        #pragma unroll
        for(int mt=0;mt<3;mt++) STORE_SPLIT(nA, mt, Z[mt]);
      }
    }
    __syncthreads();                 // all waves done reading OUT
    for(int idx=tid; idx<3072; idx+=512) nacc[idx]=0.f;
    __syncthreads();
    // ---- scatter weighted edge features to destination nodes ----
    #pragma unroll
    for(int mt=0;mt<3;mt++)
      #pragma unroll
      for(int r=0;r<4;r++){
        int dn=edst[mt*16+q*4+r];
        atomicAdd(&nacc[dn*128+nA],Z[mt][r]);
      }
  }
  __syncthreads();
  // ---- z = h + nacc, in-place split into Hh/Hl ----
  for(int idx=tid; idx<24*128; idx+=512){
    int n=idx>>7, k=idx&127;
    float zv=b2f(Hh[n*136+k])+b2f(Hl[n*136+k])+nacc[idx];
    ushort hb=f2b(zv);
    Hh[n*136+k]=hb; Hl[n*136+k]=f2b(zv-b2f(hb));
  }
  __syncthreads();
  // ---- GEMM4: out = z@wblock + b ----
  {
    f32x4 c4[2];
    c4[0]=z4; c4[1]=z4;
    #pragma unroll
    for(int kt=0;kt<4;kt++){
      int ko=kt*32+q*8;
      bf16x8 ah0=*(const bf16x8*)&Hh[ln*136+ko];
      bf16x8 ah1=*(const bf16x8*)&Hh[(16+ln)*136+ko];
      bf16x8 al0=*(const bf16x8*)&Hl[ln*136+ko];
      bf16x8 al1=*(const bf16x8*)&Hl[(16+ln)*136+ko];
      int nb=nA*128+ko;
      bf16x8 bh=*(const bf16x8*)&WbH[nb];
      bf16x8 bl=*(const bf16x8*)&WbL[nb];
      c4[0]=mfma16(ah0,bh,c4[0]);
      c4[0]=mfma16(al0,bh,c4[0]);
      c4[0]=mfma16(ah0,bl,c4[0]);
      c4[1]=mfma16(ah1,bh,c4[1]);
      c4[1]=mfma16(al1,bh,c4[1]);
      c4[1]=mfma16(ah1,bl,c4[1]);
    }
    float bbx=bblock[nA];
    #pragma unroll
    for(int mt=0;mt<2;mt++)
      #pragma unroll
      for(int r=0;r<4;r++){
        int row=mt*16+q*4+r;
        if(row<24) out[(size_t)(g*NPG+row)*128+nA]=c4[mt][r]+bbx;
      }
  }
  #undef STORE_SPLIT
}

// ---------------------------------------------------------------------------
extern "C" void kernel_launch(void* const* d_in, const int* in_sizes, int n_in,
                              void* d_out, int out_size, void* d_ws, size_t ws_size,
                              hipStream_t stream)
{
  (void)in_sizes; (void)n_in; (void)out_size; (void)ws_size;
  const float* x      = (const float*)d_in[0];
  const float* eattr  = (const float*)d_in[1];
  const int*   eidx   = (const int*)d_in[2];
  const int*   lidx   = (const int*)d_in[3];
  const float* wmlp   = (const float*)d_in[5];
  const float* bmlp   = (const float*)d_in[6];
  const float* wu     = (const float*)d_in[7];
  const float* wvv    = (const float*)d_in[8];
  const float* wedge  = (const float*)d_in[9];
  const float* wrel   = (const float*)d_in[10];
  const float* brel   = (const float*)d_in[11];
  const float* wroot  = (const float*)d_in[12];
  const float* aatt   = (const float*)d_in[13];
  const float* abias  = (const float*)d_in[14];
  const float* wgout  = (const float*)d_in[15];
  const float* bgout  = (const float*)d_in[16];
  const float* wblock = (const float*)d_in[17];
  const float* bblock = (const float*)d_in[18];

  ushort* P = (ushort*)d_ws;   // 245,760 B of pre-split weights

  k_prep <<<240, 256, 0, stream>>>(wmlp, wu, wvv, wblock, P);
  k_fused<<<NGR, 512, 0, stream>>>(x, eattr, eidx, lidx, P,
                                   bmlp, wedge, wrel, brel, wroot,
                                   aatt, abias, wgout, bgout, bblock,
                                   (float*)d_out);
}

// Round 9
// 562.792 us; speedup vs baseline: 1.3139x; 1.3139x over previous
//
#include <hip/hip_runtime.h>

#define NGR 4096
#define NPG 24
#define EPG 48
#define LPG 144
#define NITER 4
#define HID 128
#define NN (NGR*NPG)
#define NE (NGR*EPG)
#define NL (NGR*LPG)

typedef unsigned int uint;
typedef unsigned short ushort;
typedef short bf16x8 __attribute__((ext_vector_type(8)));
typedef unsigned short u16x4 __attribute__((ext_vector_type(4)));
typedef float f32x4 __attribute__((ext_vector_type(4)));
typedef float f32x2 __attribute__((ext_vector_type(2)));

__device__ __forceinline__ float b2f(ushort u){ return __uint_as_float(((uint)u)<<16); }
__device__ __forceinline__ ushort f2b(float f){
  uint x = __float_as_uint(f);
  x += 0x7FFFu + ((x>>16)&1u);
  return (ushort)(x>>16);
}
__device__ __forceinline__ float wredsum(float v){
  #pragma unroll
  for(int m=32;m;m>>=1) v += __shfl_xor(v, m, 64);
  return v;
}
__device__ __forceinline__ f32x4 mfma16(bf16x8 a, bf16x8 b, f32x4 c){
  return __builtin_amdgcn_mfma_f32_16x16x32_bf16(a, b, c, 0, 0, 0);
}

// ---------------------------------------------------------------------------
// k_prep: split weights into bf16 hi/lo, transposed [n][k], into ws.
// ushort offsets in P: WmH 0, WmL 12288, WuH 24576, WuL 40960,
//                      WvH 57344, WvL 73728, WbH 90112, WbL 106496
// ---------------------------------------------------------------------------
__global__ __launch_bounds__(256) void k_prep(
    const float* __restrict__ wmlp, const float* __restrict__ wu,
    const float* __restrict__ wv, const float* __restrict__ wb,
    ushort* __restrict__ P)
{
  int id = blockIdx.x*256 + threadIdx.x;
  if(id < 12288){
    int n=id/96, k=id-n*96;
    float v=(k<70)? wmlp[k*128+n] : 0.f;
    ushort hb=f2b(v); P[id]=hb; P[12288+id]=f2b(v-b2f(hb));
  } else if(id < 28672){
    int i=id-12288, n=i>>7, k=i&127;
    float v=wu[k*128+n]; ushort hb=f2b(v);
    P[24576+i]=hb; P[40960+i]=f2b(v-b2f(hb));
  } else if(id < 45056){
    int i=id-28672, n=i>>7, k=i&127;
    float v=wv[k*128+n]; ushort hb=f2b(v);
    P[57344+i]=hb; P[73728+i]=f2b(v-b2f(hb));
  } else if(id < 61440){
    int i=id-45056, n=i>>7, k=i&127;
    float v=wb[k*128+n]; ushort hb=f2b(v);
    P[90112+i]=hb; P[106496+i]=f2b(v-b2f(hb));
  }
}

// ---------------------------------------------------------------------------
// k_fused R9 == R7 structure with ONE change: __launch_bounds__(256,2).
// R3-R8 established: total reg demand ~190/thread; compiler splits the
// per-wave budget ~50/50 arch/AGPR; spill = demand - budget at any (N,3)/(N,4)
// config (84-slot and 64-slot arch partitions both spill). (256,2) gives a
// 256-reg budget (128 arch) -> zero spill, at 8 waves/CU (2 indep blocks).
// Single-variable experiment: does removing ~165 MB of scratch round-trips
// beat the occupancy loss 12->8 waves/CU?
// ---------------------------------------------------------------------------
__global__ __launch_bounds__(256,2) void k_fused(
  const float* __restrict__ x, const float* __restrict__ ea,
  const int* __restrict__ eidx, const int* __restrict__ lidx,
  const ushort* __restrict__ P,
  const float* __restrict__ bmlp, const float* __restrict__ wedge,
  const float* __restrict__ wrel, const float* __restrict__ brel,
  const float* __restrict__ wroot,
  const float* __restrict__ aatt, const float* __restrict__ abias,
  const float* __restrict__ wgout, const float* __restrict__ bgout,
  const float* __restrict__ bblock,
  float* __restrict__ out)
{
  const int g=blockIdx.x, tid=threadIdx.x, lane=tid&63, wid=tid>>6;
  const int q=lane>>4, ln=lane&15;
  const int E0=g*EPG, L0=g*LPG;
  const int nA = wid*32 + ln;          // this wave owns feature cols [32w,32w+32)

  __shared__ __align__(16) char LB[48320];
  ushort* Hh   = (ushort*)(LB + 0);      // h / z split hi, [24][136]
  ushort* Hl   = (ushort*)(LB + 6528);   // -> 13056
  ushort* A_bf = (ushort*)(LB + 13056);  // [48][56], cols 0..47 valid -> 18432
  ushort* OUTh = (ushort*)(LB + 18432);  // [128][48] split-hi recursion buffer
  ushort* OUTl = (ushort*)(LB + 30720);  // [128][48] split-lo -> 43008
  // aliases inside OUT region (18432..43008), sequential in time:
  ushort* A_cnt= (ushort*)(LB + 18432);  // [48][64] packed ushort counts
  ushort* xh   = (ushort*)(LB + 18432);  // [32][96]
  ushort* xl   = (ushort*)(LB + 24576);
  float*  Pe   = (float*) (LB + 30720);  // [48]   dead before pass1
  float*  Re   = (float*) (LB + 30912);  // [48]
  float*  eaL  = (float*) (LB + 31104);  // [48][6] -> 32256
  float*  nacc = (float*) (LB + 18432);  // [24][128] (after last OUT read)
  int*    esrc = (int*)   (LB + 43008);
  int*    edst = (int*)   (LB + 43200);
  float*  xcs  = (float*) (LB + 43392);  // [4][48] -> 44160
  float*  gsf  = (float*) (LB + 44160);  // [4][128] -> 46208
  float*  sfull= (float*) (LB + 46208);  // [4][128] -> 48256
  float*  score= (float*) (LB + 48256);
  float*  wts  = (float*) (LB + 48272);
  float*  zeroF= (float*) (LB + 48288);  // 8 zero floats (16B-aligned)

  const ushort *WmH=P, *WmL=P+12288, *WuH=P+24576, *WuL=P+40960,
               *WvH=P+57344, *WvL=P+73728, *WbH=P+90112, *WbL=P+106496;
  const f32x4 z4 = {0.f,0.f,0.f,0.f};

  // ---- phase 1a: x preload (regs), indices, ea, zeros, A counts ----
  f32x2 gxa[4];
  const f32x2* xg2 = (const f32x2*)(x + (size_t)g*NPG*70);
  #pragma unroll
  for(int i=0;i<4;i++){ int idx=tid+256*i; if(idx<840) gxa[i]=xg2[idx]; }
  for(int idx=tid; idx<1536; idx+=256) ((uint*)A_cnt)[idx]=0u;
  if(tid<48){
    int s=eidx[E0+tid]-g*NPG, d=eidx[NE+E0+tid]-g*NPG;
    esrc[tid]=s; edst[tid]=d; Pe[tid]=0.f; Re[tid]=0.f;
  }
  if(tid<8) zeroF[tid]=0.f;
  for(int idx=tid; idx<288; idx+=256) eaL[idx]=ea[(size_t)E0*6+idx];
  for(int idx=tid; idx<512; idx+=256) sfull[idx]=0.f;
  __syncthreads();
  if(tid<LPG){ int ls=lidx[L0+tid]-E0, ld=lidx[NL+L0+tid]-E0;
    atomicAdd(((uint*)A_cnt) + ((ld*64+ls)>>1), 1u<<((ls&1)*16)); }
  __syncthreads();
  // ---- 1b: counts -> A_bf [48][56] (cols 0..47; pad cols never read) ----
  for(int idx=tid; idx<48*48; idx+=256){ int i=idx/48, j=idx-i*48;
    A_bf[i*56+j]=f2b((float)A_cnt[i*64+j]); }
  __syncthreads();
  // ---- 1c: stage x into xh/xl (overwrites A_cnt region) ----
  #pragma unroll
  for(int i=0;i<4;i++){ int idx=tid+256*i; if(idx<840){
    int r=idx/35, c0=2*(idx-r*35);
    float v0=gxa[i].x, v1=gxa[i].y;
    ushort h0=f2b(v0), h1=f2b(v1);
    xh[r*96+c0]=h0;   xl[r*96+c0]=f2b(v0-b2f(h0));
    xh[r*96+c0+1]=h1; xl[r*96+c0+1]=f2b(v1-b2f(h1)); } }
  for(int idx=tid; idx<624; idx+=256){ int r=idx/26, c=70+(idx-r*26);
    xh[r*96+c]=0; xl[r*96+c]=0; }          // rows 24..31 left as finite garbage
  __syncthreads();

  // ---- GEMM1: h = x@wmlp + b  (bf16x3, K=96 padded) ----
  {
    f32x4 hc[2][2];
    #pragma unroll
    for(int mt=0;mt<2;mt++){ hc[mt][0]=z4; hc[mt][1]=z4; }
    #pragma unroll
    for(int kt=0; kt<3; kt++){
      int ko=kt*32+q*8;
      bf16x8 ah0=*(const bf16x8*)&xh[ln*96+ko];
      bf16x8 ah1=*(const bf16x8*)&xh[(16+ln)*96+ko];
      bf16x8 al0=*(const bf16x8*)&xl[ln*96+ko];
      bf16x8 al1=*(const bf16x8*)&xl[(16+ln)*96+ko];
      #pragma unroll
      for(int nt=0;nt<2;nt++){
        int nb=(nA+nt*16)*96+ko;
        bf16x8 bh=*(const bf16x8*)&WmH[nb];
        bf16x8 bl=*(const bf16x8*)&WmL[nb];
        hc[0][nt]=mfma16(ah0,bh,hc[0][nt]);
        hc[0][nt]=mfma16(al0,bh,hc[0][nt]);
        hc[0][nt]=mfma16(ah0,bl,hc[0][nt]);
        hc[1][nt]=mfma16(ah1,bh,hc[1][nt]);
        hc[1][nt]=mfma16(al1,bh,hc[1][nt]);
        hc[1][nt]=mfma16(ah1,bl,hc[1][nt]);
      }
    }
    float bm0=bmlp[nA], bm1=bmlp[nA+16];
    #pragma unroll
    for(int nt=0;nt<2;nt++){ float bb=nt?bm1:bm0; int col=nA+nt*16;
      #pragma unroll
      for(int mt=0;mt<2;mt++)
        #pragma unroll
        for(int r=0;r<4;r++){
          int row=mt*16+q*4+r;
          if(row<24){
            float hvv=hc[mt][nt][r]+bb;
            ushort hb=f2b(hvv);
            Hh[row*136+col]=hb; Hl[row*136+col]=f2b(hvv-b2f(hb));
          }
        }
    }
  }
  __syncthreads();

  // ---- e0 as gathered GEMM: e0 = (h[src]@wu + h[dst]@wv + ea@wedge)/3 ----
  f32x4 e0f[3][2];
  {
    int sgm[3], dgm[3];
    #pragma unroll
    for(int mt=0;mt<3;mt++){ sgm[mt]=esrc[mt*16+ln]; dgm[mt]=edst[mt*16+ln]; }
    #pragma unroll
    for(int mt=0;mt<3;mt++){ e0f[mt][0]=z4; e0f[mt][1]=z4; }
    #pragma unroll
    for(int kt=0;kt<4;kt++){
      int ko=kt*32+q*8;
      bf16x8 BuH[2],BuL[2],BvH[2],BvL[2];
      #pragma unroll
      for(int nt=0;nt<2;nt++){
        int nb=(nA+nt*16)*128+ko;
        BuH[nt]=*(const bf16x8*)&WuH[nb]; BuL[nt]=*(const bf16x8*)&WuL[nb];
        BvH[nt]=*(const bf16x8*)&WvH[nb]; BvL[nt]=*(const bf16x8*)&WvL[nb];
      }
      #pragma unroll
      for(int mt=0;mt<3;mt++){
        bf16x8 ash=*(const bf16x8*)&Hh[sgm[mt]*136+ko];
        bf16x8 asl=*(const bf16x8*)&Hl[sgm[mt]*136+ko];
        bf16x8 adh=*(const bf16x8*)&Hh[dgm[mt]*136+ko];
        bf16x8 adl=*(const bf16x8*)&Hl[dgm[mt]*136+ko];
        #pragma unroll
        for(int nt=0;nt<2;nt++){
          f32x4 acc=e0f[mt][nt];
          acc=mfma16(ash,BuH[nt],acc);
          acc=mfma16(asl,BuH[nt],acc);
          acc=mfma16(ash,BuL[nt],acc);
          acc=mfma16(adh,BvH[nt],acc);
          acc=mfma16(adl,BvH[nt],acc);
          acc=mfma16(adh,BvL[nt],acc);
          e0f[mt][nt]=acc;
        }
      }
    }
  }
  // ea@wedge term + /3, then Pe/Re partials
  {
    const float wrel0=wrel[nA], wrel1=wrel[nA+16];
    const float wroot0=wroot[nA], wroot1=wroot[nA+16];
    float wed0[6],wed1[6];
    #pragma unroll
    for(int k=0;k<6;k++){ wed0[k]=wedge[k*128+nA]; wed1[k]=wedge[k*128+nA+16]; }
    #pragma unroll
    for(int mt=0;mt<3;mt++)
      #pragma unroll
      for(int r=0;r<4;r++){
        int m=mt*16+q*4+r;
        float v0=e0f[mt][0][r], v1=e0f[mt][1][r];
        #pragma unroll
        for(int k=0;k<6;k++){ float e=eaL[m*6+k]; v0+=e*wed0[k]; v1+=e*wed1[k]; }
        e0f[mt][0][r]=v0*(1.f/3.f);
        e0f[mt][1][r]=v1*(1.f/3.f);
      }
    #pragma unroll
    for(int mt=0;mt<3;mt++)
      #pragma unroll
      for(int r=0;r<4;r++){
        float pp=e0f[mt][0][r]*wrel0  + e0f[mt][1][r]*wrel1;
        float rr=e0f[mt][0][r]*wroot0 + e0f[mt][1][r]*wroot1;
        #pragma unroll
        for(int msk=1;msk<16;msk<<=1){ pp+=__shfl_xor(pp,msk,64); rr+=__shfl_xor(rr,msk,64); }
        if(ln==0){ atomicAdd(&Pe[mt*16+q*4+r],pp); atomicAdd(&Re[mt*16+q*4+r],rr); }
      }
  }
  __syncthreads();

  // ---- wave0: xcs softmaxes (scores recursion on Pe/Re) ----
  if(wid==0){
    const float brel_f=brel[0];
    const int arow=(lane<48)?lane:0;
    float pprev=(lane<48)?Pe[lane]:0.f;
    float rprev=(lane<48)?Re[lane]:0.f;
    const float pe_l=pprev, re_l=rprev;
    float rlast=rprev;
    #pragma unroll
    for(int t=1;t<=5;t++){
      float s=0.f, sr=0.f;
      for(int j=0;j<48;j++){
        float a=b2f(A_bf[arow*56+j]);
        float pj=__shfl(pprev,j,64);
        float rj=__shfl(rprev,j,64);
        s+=a*pj; sr+=a*rj;
      }
      s+=pe_l; sr+=re_l;
      if(t>=2){
        float xv = s - pe_l + rlast + brel_f;
        float v=(lane<48)?xv:-3.0e38f;
        float mx=v;
        #pragma unroll
        for(int msk=32;msk;msk>>=1) mx=fmaxf(mx,__shfl_xor(mx,msk,64));
        float e2=(lane<48)?__expf(v-mx):0.f;
        float ss=e2;
        #pragma unroll
        for(int msk=32;msk;msk>>=1) ss+=__shfl_xor(ss,msk,64);
        if(lane<48) xcs[(t-2)*48+lane]=e2/ss;
      }
      pprev=s; rprev=sr; rlast=sr;
    }
  }
  __syncthreads();   // Pe/Re/eaL dead; OUT region free; xcs ready

  // ---- recursion helpers (swizzled split store/load, wave-private) ----
  // OUT[n][k]: row n (feature col), col k (edge). 16B block b of row n is
  // stored at block b ^ ((n>>3)&1). Wave owns rows nA, nA+16 per nt.
  #define STORE_SPLIT(n_, mt_, v_) {                                        \
    int b_ = (mt_)*2 + (q>>1);                                              \
    int off_ = (n_)*48 + ((b_ ^ (((n_)>>3)&1))<<3) + ((q&1)<<2);            \
    u16x4 hh_, ll_;                                                         \
    _Pragma("unroll")                                                       \
    for(int r_=0;r_<4;r_++){ ushort h_=f2b((v_)[r_]);                       \
      hh_[r_]=h_; ll_[r_]=f2b((v_)[r_]-b2f(h_)); }                          \
    *(u16x4*)&OUTh[off_]=hh_; *(u16x4*)&OUTl[off_]=ll_; }

  // ---- pass1: out_t = e0 + A@out_{t-1}; split-bf16 LDS round-trip ----
  f32x4 Ocur[3][2];
  #pragma unroll
  for(int mt=0;mt<3;mt++)
    #pragma unroll
    for(int nt=0;nt<2;nt++){
      int n=nA+nt*16;
      STORE_SPLIT(n, mt, e0f[mt][nt]);
    }
  #pragma unroll 1
  for(int t=0;t<NITER;t++){
    #pragma unroll
    for(int nt=0;nt<2;nt++){
      int n=nA+nt*16, sw=(n>>3)&1, base=n*48;
      bf16x8 Bh0=*(const bf16x8*)&OUTh[base+((q^sw)<<3)];
      bf16x8 Bl0=*(const bf16x8*)&OUTl[base+((q^sw)<<3)];
      const ushort* ph1=(q<2)? &OUTh[base+(((4+q)^sw)<<3)] : (const ushort*)zeroF;
      const ushort* pl1=(q<2)? &OUTl[base+(((4+q)^sw)<<3)] : (const ushort*)zeroF;
      bf16x8 Bh1=*(const bf16x8*)ph1;
      bf16x8 Bl1=*(const bf16x8*)pl1;
      #pragma unroll
      for(int mt=0;mt<3;mt++){
        int ar=(mt*16+ln)*56;
        bf16x8 a0=*(const bf16x8*)&A_bf[ar+q*8];
        const ushort* pa1=(q<2)? &A_bf[ar+32+q*8] : (const ushort*)zeroF;
        bf16x8 a1=*(const bf16x8*)pa1;
        f32x4 acc=e0f[mt][nt];
        acc=mfma16(a0,Bh0,acc);
        acc=mfma16(a1,Bh1,acc);
        acc=mfma16(a0,Bl0,acc);
        acc=mfma16(a1,Bl1,acc);
        Ocur[mt][nt]=acc;
      }
      #pragma unroll
      for(int mt=0;mt<3;mt++) STORE_SPLIT(n, mt, Ocur[mt][nt]);
    }
    float gp0=0.f, gp1=0.f;
    #pragma unroll
    for(int mt=0;mt<3;mt++)
      #pragma unroll
      for(int r=0;r<4;r++){
        float xcv=xcs[t*48+mt*16+q*4+r];
        gp0+=xcv*Ocur[mt][0][r];
        gp1+=xcv*Ocur[mt][1][r];
      }
    gp0+=__shfl_xor(gp0,16,64); gp0+=__shfl_xor(gp0,32,64);
    gp1+=__shfl_xor(gp1,16,64); gp1+=__shfl_xor(gp1,32,64);
    if(q==0){ gsf[t*128+nA]=gp0; gsf[t*128+nA+16]=gp1; }
  }
  __syncthreads();

  // ---- cooperative g@wgout partials (each wave: its own 32-k slab) ----
  {
    float p00=0,p01=0,p10=0,p11=0,p20=0,p21=0,p30=0,p31=0;
    int k0=wid*32;
    for(int kk=0;kk<32;kk++){
      int k=k0+kk;
      f32x2 w=((const f32x2*)wgout)[k*64+lane];
      float g0=gsf[k], g1=gsf[128+k], g2=gsf[256+k], g3=gsf[384+k];
      p00+=g0*w.x; p01+=g0*w.y;
      p10+=g1*w.x; p11+=g1*w.y;
      p20+=g2*w.x; p21+=g2*w.y;
      p30+=g3*w.x; p31+=g3*w.y;
    }
    atomicAdd(&sfull[2*lane],p00);     atomicAdd(&sfull[2*lane+1],p01);
    atomicAdd(&sfull[128+2*lane],p10); atomicAdd(&sfull[128+2*lane+1],p11);
    atomicAdd(&sfull[256+2*lane],p20); atomicAdd(&sfull[256+2*lane+1],p21);
    atomicAdd(&sfull[384+2*lane],p30); atomicAdd(&sfull[384+2*lane+1],p31);
  }
  __syncthreads();
  {
    int t=wid;
    float s0v=sfull[t*128+2*lane]  +bgout[2*lane];
    float s1v=sfull[t*128+2*lane+1]+bgout[2*lane+1];
    float v=tanhf(s0v)*aatt[(2*lane)*4+t]+tanhf(s1v)*aatt[(2*lane+1)*4+t];
    v=wredsum(v);
    if(lane==0) score[t]=v+abias[t];
  }
  __syncthreads();
  if(tid==0){
    float m=fmaxf(fmaxf(score[0],score[1]),fmaxf(score[2],score[3]));
    float e0v=__expf(score[0]-m), e1v=__expf(score[1]-m),
          e2v=__expf(score[2]-m), e3v=__expf(score[3]-m);
    float s=e0v+e1v+e2v+e3v;
    wts[0]=e0v/s; wts[1]=e1v/s; wts[2]=e2v/s; wts[3]=e3v/s;
  }
  __syncthreads();

  // ---- pass2 (Horner): y = sum_i c_i A^i e0, same LDS round-trip ----
  // out_t = sum_{i<=t} A^i e0  =>  sum_t w_t out_t = sum_i c_i A^i e0 with
  // c4=w4, c3=w3+w4, c2=w2+w3+w4, c1=c0=1.
  {
    const float cc4=wts[3], cc3=cc4+wts[2], cc2=cc3+wts[1];
    f32x4 Z[3][2];
    #pragma unroll
    for(int mt=0;mt<3;mt++)
      #pragma unroll
      for(int nt=0;nt<2;nt++){
        #pragma unroll
        for(int r=0;r<4;r++) Z[mt][nt][r]=cc4*e0f[mt][nt][r];
        int n=nA+nt*16;
        STORE_SPLIT(n, mt, Z[mt][nt]);
      }
    #pragma unroll 1
    for(int s=0;s<NITER;s++){
      const float ci = (s==0)?cc3:(s==1)?cc2:1.f;
      #pragma unroll
      for(int nt=0;nt<2;nt++){
        int n=nA+nt*16, sw=(n>>3)&1, base=n*48;
        bf16x8 Bh0=*(const bf16x8*)&OUTh[base+((q^sw)<<3)];
        bf16x8 Bl0=*(const bf16x8*)&OUTl[base+((q^sw)<<3)];
        const ushort* ph1=(q<2)? &OUTh[base+(((4+q)^sw)<<3)] : (const ushort*)zeroF;
        const ushort* pl1=(q<2)? &OUTl[base+(((4+q)^sw)<<3)] : (const ushort*)zeroF;
        bf16x8 Bh1=*(const bf16x8*)ph1;
        bf16x8 Bl1=*(const bf16x8*)pl1;
        #pragma unroll
        for(int mt=0;mt<3;mt++){
          int ar=(mt*16+ln)*56;
          bf16x8 a0=*(const bf16x8*)&A_bf[ar+q*8];
          const ushort* pa1=(q<2)? &A_bf[ar+32+q*8] : (const ushort*)zeroF;
          bf16x8 a1=*(const bf16x8*)pa1;
          f32x4 acc;
          #pragma unroll
          for(int r=0;r<4;r++) acc[r]=ci*e0f[mt][nt][r];
          acc=mfma16(a0,Bh0,acc);
          acc=mfma16(a1,Bh1,acc);
          acc=mfma16(a0,Bl0,acc);
          acc=mfma16(a1,Bl1,acc);
          Z[mt][nt]=acc;
        }
        if(s<NITER-1){
          #pragma unroll
          for(int mt=0;mt<3;mt++) STORE_SPLIT(n, mt, Z[mt][nt]);
        }
      }
    }
    __syncthreads();                 // all waves done reading OUT
    for(int idx=tid; idx<3072; idx+=256) nacc[idx]=0.f;
    __syncthreads();
    // ---- scatter weighted edge features to destination nodes ----
    #pragma unroll
    for(int mt=0;mt<3;mt++)
      #pragma unroll
      for(int nt=0;nt<2;nt++){
        int ncol=nA+nt*16;
        #pragma unroll
        for(int r=0;r<4;r++){
          int dn=edst[mt*16+q*4+r];
          atomicAdd(&nacc[dn*128+ncol],Z[mt][nt][r]);
        }
      }
  }
  __syncthreads();
  // ---- z = h + nacc, in-place split into Hh/Hl ----
  for(int idx=tid; idx<24*128; idx+=256){
    int n=idx>>7, k=idx&127;
    float zv=b2f(Hh[n*136+k])+b2f(Hl[n*136+k])+nacc[idx];
    ushort hb=f2b(zv);
    Hh[n*136+k]=hb; Hl[n*136+k]=f2b(zv-b2f(hb));
  }
  __syncthreads();
  // ---- GEMM4: out = z@wblock + b ----
  {
    f32x4 c4[2][2];
    c4[0][0]=z4; c4[0][1]=z4; c4[1][0]=z4; c4[1][1]=z4;
    #pragma unroll
    for(int kt=0;kt<4;kt++){
      int ko=kt*32+q*8;
      bf16x8 ah0=*(const bf16x8*)&Hh[ln*136+ko];
      bf16x8 ah1=*(const bf16x8*)&Hh[(16+ln)*136+ko];
      bf16x8 al0=*(const bf16x8*)&Hl[ln*136+ko];
      bf16x8 al1=*(const bf16x8*)&Hl[(16+ln)*136+ko];
      #pragma unroll
      for(int nt=0;nt<2;nt++){
        int nb=(nA+nt*16)*128+ko;
        bf16x8 bh=*(const bf16x8*)&WbH[nb];
        bf16x8 bl=*(const bf16x8*)&WbL[nb];
        c4[0][nt]=mfma16(ah0,bh,c4[0][nt]);
        c4[0][nt]=mfma16(al0,bh,c4[0][nt]);
        c4[0][nt]=mfma16(ah0,bl,c4[0][nt]);
        c4[1][nt]=mfma16(ah1,bh,c4[1][nt]);
        c4[1][nt]=mfma16(al1,bh,c4[1][nt]);
        c4[1][nt]=mfma16(ah1,bl,c4[1][nt]);
      }
    }
    float bb0=bblock[nA], bb1=bblock[nA+16];
    #pragma unroll
    for(int nt=0;nt<2;nt++){ float bbx=nt?bb1:bb0; int col=nA+nt*16;
      #pragma unroll
      for(int mt=0;mt<2;mt++)
        #pragma unroll
        for(int r=0;r<4;r++){
          int row=mt*16+q*4+r;
          if(row<24) out[(size_t)(g*NPG+row)*128+col]=c4[mt][nt][r]+bbx;
        }
    }
  }
  #undef STORE_SPLIT
}

// ---------------------------------------------------------------------------
extern "C" void kernel_launch(void* const* d_in, const int* in_sizes, int n_in,
                              void* d_out, int out_size, void* d_ws, size_t ws_size,
                              hipStream_t stream)
{
  (void)in_sizes; (void)n_in; (void)out_size; (void)ws_size;
  const float* x      = (const float*)d_in[0];
  const float* eattr  = (const float*)d_in[1];
  const int*   eidx   = (const int*)d_in[2];
  const int*   lidx   = (const int*)d_in[3];
  const float* wmlp   = (const float*)d_in[5];
  const float* bmlp   = (const float*)d_in[6];
  const float* wu     = (const float*)d_in[7];
  const float* wvv    = (const float*)d_in[8];
  const float* wedge  = (const float*)d_in[9];
  const float* wrel   = (const float*)d_in[10];
  const float* brel   = (const float*)d_in[11];
  const float* wroot  = (const float*)d_in[12];
  const float* aatt   = (const float*)d_in[13];
  const float* abias  = (const float*)d_in[14];
  const float* wgout  = (const float*)d_in[15];
  const float* bgout  = (const float*)d_in[16];
  const float* wblock = (const float*)d_in[17];
  const float* bblock = (const float*)d_in[18];

  ushort* P = (ushort*)d_ws;   // 245,760 B of pre-split weights

  k_prep <<<240, 256, 0, stream>>>(wmlp, wu, wvv, wblock, P);
  k_fused<<<NGR, 256, 0, stream>>>(x, eattr, eidx, lidx, P,
                                   bmlp, wedge, wrel, brel, wroot,
                                   aatt, abias, wgout, bgout, bblock,
                                   (float*)d_out);
}

// Round 10
// 532.134 us; speedup vs baseline: 1.3896x; 1.0576x over previous
//
#include <hip/hip_runtime.h>

#define NGR 4096
#define NPG 24
#define EPG 48
#define LPG 144
#define NITER 4
#define HID 128
#define NN (NGR*NPG)
#define NE (NGR*EPG)
#define NL (NGR*LPG)

typedef unsigned int uint;
typedef unsigned short ushort;
typedef short bf16x8 __attribute__((ext_vector_type(8)));
typedef unsigned short u16x4 __attribute__((ext_vector_type(4)));
typedef float f32x4 __attribute__((ext_vector_type(4)));
typedef float f32x2 __attribute__((ext_vector_type(2)));

__device__ __forceinline__ float b2f(ushort u){ return __uint_as_float(((uint)u)<<16); }
__device__ __forceinline__ ushort f2b(float f){
  uint x = __float_as_uint(f);
  x += 0x7FFFu + ((x>>16)&1u);
  return (ushort)(x>>16);
}
__device__ __forceinline__ float wredsum(float v){
  #pragma unroll
  for(int m=32;m;m>>=1) v += __shfl_xor(v, m, 64);
  return v;
}
__device__ __forceinline__ f32x4 mfma16(bf16x8 a, bf16x8 b, f32x4 c){
  return __builtin_amdgcn_mfma_f32_16x16x32_bf16(a, b, c, 0, 0, 0);
}

// ---------------------------------------------------------------------------
// k_prep: split weights into bf16 hi/lo, transposed [n][k], into ws.
// ushort offsets in P: WmH 0, WmL 12288, WuH 24576, WuL 40960,
//                      WvH 57344, WvL 73728, WbH 90112, WbL 106496
// ---------------------------------------------------------------------------
__global__ __launch_bounds__(256) void k_prep(
    const float* __restrict__ wmlp, const float* __restrict__ wu,
    const float* __restrict__ wv, const float* __restrict__ wb,
    ushort* __restrict__ P)
{
  int id = blockIdx.x*256 + threadIdx.x;
  if(id < 12288){
    int n=id/96, k=id-n*96;
    float v=(k<70)? wmlp[k*128+n] : 0.f;
    ushort hb=f2b(v); P[id]=hb; P[12288+id]=f2b(v-b2f(hb));
  } else if(id < 28672){
    int i=id-12288, n=i>>7, k=i&127;
    float v=wu[k*128+n]; ushort hb=f2b(v);
    P[24576+i]=hb; P[40960+i]=f2b(v-b2f(hb));
  } else if(id < 45056){
    int i=id-28672, n=i>>7, k=i&127;
    float v=wv[k*128+n]; ushort hb=f2b(v);
    P[57344+i]=hb; P[73728+i]=f2b(v-b2f(hb));
  } else if(id < 61440){
    int i=id-45056, n=i>>7, k=i&127;
    float v=wb[k*128+n]; ushort hb=f2b(v);
    P[90112+i]=hb; P[106496+i]=f2b(v-b2f(hb));
  }
}

// ---------------------------------------------------------------------------
// k_fused R10 = R9 (clean traffic at (256,2), 256-reg budget) + register-
// resident history: pass2 (Horner re-run) DELETED. Pass1 keeps out_1..out_3
// snapshots in named reg arrays h0/h1/h2 (uniform-t branch writes, static
// indexing only), final y = w1*h0+w2*h1+w3*h2+w4*Ocur. Removes 96 MFMA/wave,
// 4 serial LDS round-trips, ~40% of bank conflicts. nacc zeroing overlapped
// with the score/wts phase. Traffic signature must stay FETCH~21/WRITE~49 MB.
// ---------------------------------------------------------------------------
__global__ __launch_bounds__(256,2) void k_fused(
  const float* __restrict__ x, const float* __restrict__ ea,
  const int* __restrict__ eidx, const int* __restrict__ lidx,
  const ushort* __restrict__ P,
  const float* __restrict__ bmlp, const float* __restrict__ wedge,
  const float* __restrict__ wrel, const float* __restrict__ brel,
  const float* __restrict__ wroot,
  const float* __restrict__ aatt, const float* __restrict__ abias,
  const float* __restrict__ wgout, const float* __restrict__ bgout,
  const float* __restrict__ bblock,
  float* __restrict__ out)
{
  const int g=blockIdx.x, tid=threadIdx.x, lane=tid&63, wid=tid>>6;
  const int q=lane>>4, ln=lane&15;
  const int E0=g*EPG, L0=g*LPG;
  const int nA = wid*32 + ln;          // this wave owns feature cols [32w,32w+32)

  __shared__ __align__(16) char LB[48320];
  ushort* Hh   = (ushort*)(LB + 0);      // h / z split hi, [24][136]
  ushort* Hl   = (ushort*)(LB + 6528);   // -> 13056
  ushort* A_bf = (ushort*)(LB + 13056);  // [48][56], cols 0..47 valid -> 18432
  ushort* OUTh = (ushort*)(LB + 18432);  // [128][48] split-hi recursion buffer
  ushort* OUTl = (ushort*)(LB + 30720);  // [128][48] split-lo -> 43008
  // aliases inside OUT region (18432..43008), sequential in time:
  ushort* A_cnt= (ushort*)(LB + 18432);  // [48][64] packed ushort counts
  ushort* xh   = (ushort*)(LB + 18432);  // [32][96]
  ushort* xl   = (ushort*)(LB + 24576);
  float*  Pe   = (float*) (LB + 30720);  // [48]   dead before pass1
  float*  Re   = (float*) (LB + 30912);  // [48]
  float*  eaL  = (float*) (LB + 31104);  // [48][6] -> 32256
  float*  nacc = (float*) (LB + 18432);  // [24][128] (after last OUT read)
  int*    esrc = (int*)   (LB + 43008);
  int*    edst = (int*)   (LB + 43200);
  float*  xcs  = (float*) (LB + 43392);  // [4][48] -> 44160
  float*  gsf  = (float*) (LB + 44160);  // [4][128] -> 46208
  float*  sfull= (float*) (LB + 46208);  // [4][128] -> 48256
  float*  score= (float*) (LB + 48256);
  float*  wts  = (float*) (LB + 48272);
  float*  zeroF= (float*) (LB + 48288);  // 8 zero floats (16B-aligned)

  const ushort *WmH=P, *WmL=P+12288, *WuH=P+24576, *WuL=P+40960,
               *WvH=P+57344, *WvL=P+73728, *WbH=P+90112, *WbL=P+106496;
  const f32x4 z4 = {0.f,0.f,0.f,0.f};

  // ---- phase 1a: x preload (regs), indices, ea, zeros, A counts ----
  f32x2 gxa[4];
  const f32x2* xg2 = (const f32x2*)(x + (size_t)g*NPG*70);
  #pragma unroll
  for(int i=0;i<4;i++){ int idx=tid+256*i; if(idx<840) gxa[i]=xg2[idx]; }
  for(int idx=tid; idx<1536; idx+=256) ((uint*)A_cnt)[idx]=0u;
  if(tid<48){
    int s=eidx[E0+tid]-g*NPG, d=eidx[NE+E0+tid]-g*NPG;
    esrc[tid]=s; edst[tid]=d; Pe[tid]=0.f; Re[tid]=0.f;
  }
  if(tid<8) zeroF[tid]=0.f;
  for(int idx=tid; idx<288; idx+=256) eaL[idx]=ea[(size_t)E0*6+idx];
  for(int idx=tid; idx<512; idx+=256) sfull[idx]=0.f;
  __syncthreads();
  if(tid<LPG){ int ls=lidx[L0+tid]-E0, ld=lidx[NL+L0+tid]-E0;
    atomicAdd(((uint*)A_cnt) + ((ld*64+ls)>>1), 1u<<((ls&1)*16)); }
  __syncthreads();
  // ---- 1b: counts -> A_bf [48][56] (cols 0..47; pad cols never read) ----
  for(int idx=tid; idx<48*48; idx+=256){ int i=idx/48, j=idx-i*48;
    A_bf[i*56+j]=f2b((float)A_cnt[i*64+j]); }
  __syncthreads();
  // ---- 1c: stage x into xh/xl (overwrites A_cnt region) ----
  #pragma unroll
  for(int i=0;i<4;i++){ int idx=tid+256*i; if(idx<840){
    int r=idx/35, c0=2*(idx-r*35);
    float v0=gxa[i].x, v1=gxa[i].y;
    ushort h0v=f2b(v0), h1v=f2b(v1);
    xh[r*96+c0]=h0v;   xl[r*96+c0]=f2b(v0-b2f(h0v));
    xh[r*96+c0+1]=h1v; xl[r*96+c0+1]=f2b(v1-b2f(h1v)); } }
  for(int idx=tid; idx<624; idx+=256){ int r=idx/26, c=70+(idx-r*26);
    xh[r*96+c]=0; xl[r*96+c]=0; }          // rows 24..31 left as finite garbage
  __syncthreads();

  // ---- GEMM1: h = x@wmlp + b  (bf16x3, K=96 padded) ----
  {
    f32x4 hc[2][2];
    #pragma unroll
    for(int mt=0;mt<2;mt++){ hc[mt][0]=z4; hc[mt][1]=z4; }
    #pragma unroll
    for(int kt=0; kt<3; kt++){
      int ko=kt*32+q*8;
      bf16x8 ah0=*(const bf16x8*)&xh[ln*96+ko];
      bf16x8 ah1=*(const bf16x8*)&xh[(16+ln)*96+ko];
      bf16x8 al0=*(const bf16x8*)&xl[ln*96+ko];
      bf16x8 al1=*(const bf16x8*)&xl[(16+ln)*96+ko];
      #pragma unroll
      for(int nt=0;nt<2;nt++){
        int nb=(nA+nt*16)*96+ko;
        bf16x8 bh=*(const bf16x8*)&WmH[nb];
        bf16x8 bl=*(const bf16x8*)&WmL[nb];
        hc[0][nt]=mfma16(ah0,bh,hc[0][nt]);
        hc[0][nt]=mfma16(al0,bh,hc[0][nt]);
        hc[0][nt]=mfma16(ah0,bl,hc[0][nt]);
        hc[1][nt]=mfma16(ah1,bh,hc[1][nt]);
        hc[1][nt]=mfma16(al1,bh,hc[1][nt]);
        hc[1][nt]=mfma16(ah1,bl,hc[1][nt]);
      }
    }
    float bm0=bmlp[nA], bm1=bmlp[nA+16];
    #pragma unroll
    for(int nt=0;nt<2;nt++){ float bb=nt?bm1:bm0; int col=nA+nt*16;
      #pragma unroll
      for(int mt=0;mt<2;mt++)
        #pragma unroll
        for(int r=0;r<4;r++){
          int row=mt*16+q*4+r;
          if(row<24){
            float hvv=hc[mt][nt][r]+bb;
            ushort hb=f2b(hvv);
            Hh[row*136+col]=hb; Hl[row*136+col]=f2b(hvv-b2f(hb));
          }
        }
    }
  }
  __syncthreads();

  // ---- e0 as gathered GEMM: e0 = (h[src]@wu + h[dst]@wv + ea@wedge)/3 ----
  f32x4 e0f[3][2];
  {
    int sgm[3], dgm[3];
    #pragma unroll
    for(int mt=0;mt<3;mt++){ sgm[mt]=esrc[mt*16+ln]; dgm[mt]=edst[mt*16+ln]; }
    #pragma unroll
    for(int mt=0;mt<3;mt++){ e0f[mt][0]=z4; e0f[mt][1]=z4; }
    #pragma unroll
    for(int kt=0;kt<4;kt++){
      int ko=kt*32+q*8;
      bf16x8 BuH[2],BuL[2],BvH[2],BvL[2];
      #pragma unroll
      for(int nt=0;nt<2;nt++){
        int nb=(nA+nt*16)*128+ko;
        BuH[nt]=*(const bf16x8*)&WuH[nb]; BuL[nt]=*(const bf16x8*)&WuL[nb];
        BvH[nt]=*(const bf16x8*)&WvH[nb]; BvL[nt]=*(const bf16x8*)&WvL[nb];
      }
      #pragma unroll
      for(int mt=0;mt<3;mt++){
        bf16x8 ash=*(const bf16x8*)&Hh[sgm[mt]*136+ko];
        bf16x8 asl=*(const bf16x8*)&Hl[sgm[mt]*136+ko];
        bf16x8 adh=*(const bf16x8*)&Hh[dgm[mt]*136+ko];
        bf16x8 adl=*(const bf16x8*)&Hl[dgm[mt]*136+ko];
        #pragma unroll
        for(int nt=0;nt<2;nt++){
          f32x4 acc=e0f[mt][nt];
          acc=mfma16(ash,BuH[nt],acc);
          acc=mfma16(asl,BuH[nt],acc);
          acc=mfma16(ash,BuL[nt],acc);
          acc=mfma16(adh,BvH[nt],acc);
          acc=mfma16(adl,BvH[nt],acc);
          acc=mfma16(adh,BvL[nt],acc);
          e0f[mt][nt]=acc;
        }
      }
    }
  }
  // ea@wedge term + /3, then Pe/Re partials
  {
    const float wrel0=wrel[nA], wrel1=wrel[nA+16];
    const float wroot0=wroot[nA], wroot1=wroot[nA+16];
    float wed0[6],wed1[6];
    #pragma unroll
    for(int k=0;k<6;k++){ wed0[k]=wedge[k*128+nA]; wed1[k]=wedge[k*128+nA+16]; }
    #pragma unroll
    for(int mt=0;mt<3;mt++)
      #pragma unroll
      for(int r=0;r<4;r++){
        int m=mt*16+q*4+r;
        float v0=e0f[mt][0][r], v1=e0f[mt][1][r];
        #pragma unroll
        for(int k=0;k<6;k++){ float e=eaL[m*6+k]; v0+=e*wed0[k]; v1+=e*wed1[k]; }
        e0f[mt][0][r]=v0*(1.f/3.f);
        e0f[mt][1][r]=v1*(1.f/3.f);
      }
    #pragma unroll
    for(int mt=0;mt<3;mt++)
      #pragma unroll
      for(int r=0;r<4;r++){
        float pp=e0f[mt][0][r]*wrel0  + e0f[mt][1][r]*wrel1;
        float rr=e0f[mt][0][r]*wroot0 + e0f[mt][1][r]*wroot1;
        #pragma unroll
        for(int msk=1;msk<16;msk<<=1){ pp+=__shfl_xor(pp,msk,64); rr+=__shfl_xor(rr,msk,64); }
        if(ln==0){ atomicAdd(&Pe[mt*16+q*4+r],pp); atomicAdd(&Re[mt*16+q*4+r],rr); }
      }
  }
  __syncthreads();

  // ---- wave0: xcs softmaxes (scores recursion on Pe/Re) ----
  if(wid==0){
    const float brel_f=brel[0];
    const int arow=(lane<48)?lane:0;
    float pprev=(lane<48)?Pe[lane]:0.f;
    float rprev=(lane<48)?Re[lane]:0.f;
    const float pe_l=pprev, re_l=rprev;
    float rlast=rprev;
    #pragma unroll
    for(int t=1;t<=5;t++){
      float s=0.f, sr=0.f;
      for(int j=0;j<48;j++){
        float a=b2f(A_bf[arow*56+j]);
        float pj=__shfl(pprev,j,64);
        float rj=__shfl(rprev,j,64);
        s+=a*pj; sr+=a*rj;
      }
      s+=pe_l; sr+=re_l;
      if(t>=2){
        float xv = s - pe_l + rlast + brel_f;
        float v=(lane<48)?xv:-3.0e38f;
        float mx=v;
        #pragma unroll
        for(int msk=32;msk;msk>>=1) mx=fmaxf(mx,__shfl_xor(mx,msk,64));
        float e2=(lane<48)?__expf(v-mx):0.f;
        float ss=e2;
        #pragma unroll
        for(int msk=32;msk;msk>>=1) ss+=__shfl_xor(ss,msk,64);
        if(lane<48) xcs[(t-2)*48+lane]=e2/ss;
      }
      pprev=s; rprev=sr; rlast=sr;
    }
  }
  __syncthreads();   // Pe/Re/eaL dead; OUT region free; xcs ready

  // ---- recursion helpers (swizzled split store/load, wave-private) ----
  // OUT[n][k]: row n (feature col), col k (edge). 16B block b of row n is
  // stored at block b ^ ((n>>3)&1). Wave owns rows nA, nA+16 per nt.
  #define STORE_SPLIT(n_, mt_, v_) {                                        \
    int b_ = (mt_)*2 + (q>>1);                                              \
    int off_ = (n_)*48 + ((b_ ^ (((n_)>>3)&1))<<3) + ((q&1)<<2);            \
    u16x4 hh_, ll_;                                                         \
    _Pragma("unroll")                                                       \
    for(int r_=0;r_<4;r_++){ ushort h_=f2b((v_)[r_]);                       \
      hh_[r_]=h_; ll_[r_]=f2b((v_)[r_]-b2f(h_)); }                          \
    *(u16x4*)&OUTh[off_]=hh_; *(u16x4*)&OUTl[off_]=ll_; }

  // ---- pass1 (ONLY pass): out_t = e0 + A@out_{t-1}; reg-resident history ----
  f32x4 Ocur[3][2];
  f32x4 h0[3][2], h1[3][2], h2[3][2];     // out_1..out_3 snapshots (static idx)
  #pragma unroll
  for(int mt=0;mt<3;mt++)
    #pragma unroll
    for(int nt=0;nt<2;nt++){
      int n=nA+nt*16;
      STORE_SPLIT(n, mt, e0f[mt][nt]);
    }
  #pragma unroll 1
  for(int t=0;t<NITER;t++){
    #pragma unroll
    for(int nt=0;nt<2;nt++){
      int n=nA+nt*16, sw=(n>>3)&1, base=n*48;
      bf16x8 Bh0=*(const bf16x8*)&OUTh[base+((q^sw)<<3)];
      bf16x8 Bl0=*(const bf16x8*)&OUTl[base+((q^sw)<<3)];
      const ushort* ph1=(q<2)? &OUTh[base+(((4+q)^sw)<<3)] : (const ushort*)zeroF;
      const ushort* pl1=(q<2)? &OUTl[base+(((4+q)^sw)<<3)] : (const ushort*)zeroF;
      bf16x8 Bh1=*(const bf16x8*)ph1;
      bf16x8 Bl1=*(const bf16x8*)pl1;
      #pragma unroll
      for(int mt=0;mt<3;mt++){
        int ar=(mt*16+ln)*56;
        bf16x8 a0=*(const bf16x8*)&A_bf[ar+q*8];
        const ushort* pa1=(q<2)? &A_bf[ar+32+q*8] : (const ushort*)zeroF;
        bf16x8 a1=*(const bf16x8*)pa1;
        f32x4 acc=e0f[mt][nt];
        acc=mfma16(a0,Bh0,acc);
        acc=mfma16(a1,Bh1,acc);
        acc=mfma16(a0,Bl0,acc);
        acc=mfma16(a1,Bl1,acc);
        Ocur[mt][nt]=acc;
      }
      if(t<NITER-1){
        #pragma unroll
        for(int mt=0;mt<3;mt++) STORE_SPLIT(n, mt, Ocur[mt][nt]);
      }
    }
    // snapshot (uniform-t branches, static indexing only)
    if(t==0){
      #pragma unroll
      for(int mt=0;mt<3;mt++){ h0[mt][0]=Ocur[mt][0]; h0[mt][1]=Ocur[mt][1]; }
    } else if(t==1){
      #pragma unroll
      for(int mt=0;mt<3;mt++){ h1[mt][0]=Ocur[mt][0]; h1[mt][1]=Ocur[mt][1]; }
    } else if(t==2){
      #pragma unroll
      for(int mt=0;mt<3;mt++){ h2[mt][0]=Ocur[mt][0]; h2[mt][1]=Ocur[mt][1]; }
    }
    float gp0=0.f, gp1=0.f;
    #pragma unroll
    for(int mt=0;mt<3;mt++)
      #pragma unroll
      for(int r=0;r<4;r++){
        float xcv=xcs[t*48+mt*16+q*4+r];
        gp0+=xcv*Ocur[mt][0][r];
        gp1+=xcv*Ocur[mt][1][r];
      }
    gp0+=__shfl_xor(gp0,16,64); gp0+=__shfl_xor(gp0,32,64);
    gp1+=__shfl_xor(gp1,16,64); gp1+=__shfl_xor(gp1,32,64);
    if(q==0){ gsf[t*128+nA]=gp0; gsf[t*128+nA+16]=gp1; }
  }
  __syncthreads();   // gsf ready; all OUT reads done -> OUT region dead

  // ---- zero nacc (overlapped with score phase; OUT dead) ----
  for(int idx=tid; idx<3072; idx+=256) nacc[idx]=0.f;

  // ---- cooperative g@wgout partials (each wave: its own 32-k slab) ----
  {
    float p00=0,p01=0,p10=0,p11=0,p20=0,p21=0,p30=0,p31=0;
    int k0=wid*32;
    for(int kk=0;kk<32;kk++){
      int k=k0+kk;
      f32x2 w=((const f32x2*)wgout)[k*64+lane];
      float g0=gsf[k], g1=gsf[128+k], g2=gsf[256+k], g3=gsf[384+k];
      p00+=g0*w.x; p01+=g0*w.y;
      p10+=g1*w.x; p11+=g1*w.y;
      p20+=g2*w.x; p21+=g2*w.y;
      p30+=g3*w.x; p31+=g3*w.y;
    }
    atomicAdd(&sfull[2*lane],p00);     atomicAdd(&sfull[2*lane+1],p01);
    atomicAdd(&sfull[128+2*lane],p10); atomicAdd(&sfull[128+2*lane+1],p11);
    atomicAdd(&sfull[256+2*lane],p20); atomicAdd(&sfull[256+2*lane+1],p21);
    atomicAdd(&sfull[384+2*lane],p30); atomicAdd(&sfull[384+2*lane+1],p31);
  }
  __syncthreads();
  {
    int t=wid;
    float s0v=sfull[t*128+2*lane]  +bgout[2*lane];
    float s1v=sfull[t*128+2*lane+1]+bgout[2*lane+1];
    float v=tanhf(s0v)*aatt[(2*lane)*4+t]+tanhf(s1v)*aatt[(2*lane+1)*4+t];
    v=wredsum(v);
    if(lane==0) score[t]=v+abias[t];
  }
  __syncthreads();
  if(tid==0){
    float m=fmaxf(fmaxf(score[0],score[1]),fmaxf(score[2],score[3]));
    float e0v=__expf(score[0]-m), e1v=__expf(score[1]-m),
          e2v=__expf(score[2]-m), e3v=__expf(score[3]-m);
    float s=e0v+e1v+e2v+e3v;
    wts[0]=e0v/s; wts[1]=e1v/s; wts[2]=e2v/s; wts[3]=e3v/s;
  }
  __syncthreads();

  // ---- weighted temporal sum from register history -> node scatter ----
  {
    const float w1=wts[0], w2=wts[1], w3=wts[2], w4=wts[3];
    #pragma unroll
    for(int mt=0;mt<3;mt++)
      #pragma unroll
      for(int nt=0;nt<2;nt++){
        int ncol=nA+nt*16;
        #pragma unroll
        for(int r=0;r<4;r++){
          float wv=w1*h0[mt][nt][r]+w2*h1[mt][nt][r]
                  +w3*h2[mt][nt][r]+w4*Ocur[mt][nt][r];
          int dn=edst[mt*16+q*4+r];
          atomicAdd(&nacc[dn*128+ncol],wv);
        }
      }
  }
  __syncthreads();
  // ---- z = h + nacc, in-place split into Hh/Hl ----
  for(int idx=tid; idx<24*128; idx+=256){
    int n=idx>>7, k=idx&127;
    float zv=b2f(Hh[n*136+k])+b2f(Hl[n*136+k])+nacc[idx];
    ushort hb=f2b(zv);
    Hh[n*136+k]=hb; Hl[n*136+k]=f2b(zv-b2f(hb));
  }
  __syncthreads();
  // ---- GEMM4: out = z@wblock + b ----
  {
    f32x4 c4[2][2];
    c4[0][0]=z4; c4[0][1]=z4; c4[1][0]=z4; c4[1][1]=z4;
    #pragma unroll
    for(int kt=0;kt<4;kt++){
      int ko=kt*32+q*8;
      bf16x8 ah0=*(const bf16x8*)&Hh[ln*136+ko];
      bf16x8 ah1=*(const bf16x8*)&Hh[(16+ln)*136+ko];
      bf16x8 al0=*(const bf16x8*)&Hl[ln*136+ko];
      bf16x8 al1=*(const bf16x8*)&Hl[(16+ln)*136+ko];
      #pragma unroll
      for(int nt=0;nt<2;nt++){
        int nb=(nA+nt*16)*128+ko;
        bf16x8 bh=*(const bf16x8*)&WbH[nb];
        bf16x8 bl=*(const bf16x8*)&WbL[nb];
        c4[0][nt]=mfma16(ah0,bh,c4[0][nt]);
        c4[0][nt]=mfma16(al0,bh,c4[0][nt]);
        c4[0][nt]=mfma16(ah0,bl,c4[0][nt]);
        c4[1][nt]=mfma16(ah1,bh,c4[1][nt]);
        c4[1][nt]=mfma16(al1,bh,c4[1][nt]);
        c4[1][nt]=mfma16(ah1,bl,c4[1][nt]);
      }
    }
    float bb0=bblock[nA], bb1=bblock[nA+16];
    #pragma unroll
    for(int nt=0;nt<2;nt++){ float bbx=nt?bb1:bb0; int col=nA+nt*16;
      #pragma unroll
      for(int mt=0;mt<2;mt++)
        #pragma unroll
        for(int r=0;r<4;r++){
          int row=mt*16+q*4+r;
          if(row<24) out[(size_t)(g*NPG+row)*128+col]=c4[mt][nt][r]+bbx;
        }
    }
  }
  #undef STORE_SPLIT
}

// ---------------------------------------------------------------------------
extern "C" void kernel_launch(void* const* d_in, const int* in_sizes, int n_in,
                              void* d_out, int out_size, void* d_ws, size_t ws_size,
                              hipStream_t stream)
{
  (void)in_sizes; (void)n_in; (void)out_size; (void)ws_size;
  const float* x      = (const float*)d_in[0];
  const float* eattr  = (const float*)d_in[1];
  const int*   eidx   = (const int*)d_in[2];
  const int*   lidx   = (const int*)d_in[3];
  const float* wmlp   = (const float*)d_in[5];
  const float* bmlp   = (const float*)d_in[6];
  const float* wu     = (const float*)d_in[7];
  const float* wvv    = (const float*)d_in[8];
  const float* wedge  = (const float*)d_in[9];
  const float* wrel   = (const float*)d_in[10];
  const float* brel   = (const float*)d_in[11];
  const float* wroot  = (const float*)d_in[12];
  const float* aatt   = (const float*)d_in[13];
  const float* abias  = (const float*)d_in[14];
  const float* wgout  = (const float*)d_in[15];
  const float* bgout  = (const float*)d_in[16];
  const float* wblock = (const float*)d_in[17];
  const float* bblock = (const float*)d_in[18];

  ushort* P = (ushort*)d_ws;   // 245,760 B of pre-split weights

  k_prep <<<240, 256, 0, stream>>>(wmlp, wu, wvv, wblock, P);
  k_fused<<<NGR, 256, 0, stream>>>(x, eattr, eidx, lidx, P,
                                   bmlp, wedge, wrel, brel, wroot,
                                   aatt, abias, wgout, bgout, bblock,
                                   (float*)d_out);
}